// Round 3
// baseline (687.782 us; speedup 1.0000x reference)
//
#include <hip/hip_runtime.h>

// Problem dims
#define BB 64
#define SS 2048
#define INDIM 256
#define HH 512
#define EE 256
#define OUTD 32000

typedef __attribute__((ext_vector_type(8))) short short8;
typedef __attribute__((ext_vector_type(4))) float floatx4;

#define LOG2E 1.4426950408889634f

// ---- helpers ----
__device__ __forceinline__ unsigned short f2bf(float f) {
  unsigned u = __float_as_uint(f);
  return (unsigned short)((u + 0x7FFFu + ((u >> 16) & 1u)) >> 16);  // RNE
}
__device__ __forceinline__ unsigned pk2(float a, float b) {
  return (unsigned)f2bf(a) | ((unsigned)f2bf(b) << 16);
}
__device__ __forceinline__ float bf2f(unsigned short u) {
  return __uint_as_float((unsigned)u << 16);
}
__device__ __forceinline__ float fast_tanh(float x) {
  float e = __builtin_amdgcn_exp2f(x * 2.8853900817779268f);
  return 1.0f - 2.0f * __builtin_amdgcn_rcpf(e + 1.0f);
}
__device__ __forceinline__ float fast_sigmoid(float x) {
  float e = __builtin_amdgcn_exp2f(-x * LOG2E);
  return __builtin_amdgcn_rcpf(1.0f + e);
}

// ws layout (bytes)
#define WS_W1T   0          // 256x512 bf16 W1^T            : 524288? (262144)
#define WS_HB    262144     // 64x256 f32                   : 65536
#define WS_CTX   327680     // 64x512 f32 normalized ctx    : 131072
#define WS_NHBF  458752     // 64x512 bf16 new hidden       : 65536
#define WS_Z     589824     // 64x512 f32 update gate       : 131072
#define WS_RH    720896     // 64x512 f32 r*hidden          : 131072
#define WS_CTXP  1048576    // 2048x512 f32 ctx partials    : 4194304
#define WS_SUMP  5242880    // 2048 f32 exp-sum partials    : 8192

// ---- prep: transpose+convert W1 -> bf16 [e][k] ----
__global__ void k_prep(const float* __restrict__ W1, unsigned short* __restrict__ W1t) {
  int idx = blockIdx.x * 256 + threadIdx.x;   // idx = k*256 + e (coalesced read)
  int k = idx >> 8, e = idx & 255;
  W1t[e * HH + k] = f2bf(W1[idx]);
}

// ---- hb[b][e] = W1_b[e] + hidden[b]@W2[:,e]; 4 batches per block ----
__global__ __launch_bounds__(256) void k_hb(const float* __restrict__ hidden,
                                            const float* __restrict__ W2,
                                            const float* __restrict__ W1b,
                                            float* __restrict__ hb) {
  int b0 = blockIdx.x * 4, e = threadIdx.x;
  float bias = W1b[e];
  float a0 = bias, a1 = bias, a2 = bias, a3 = bias;
  for (int h = 0; h < HH; ++h) {
    float w = W2[h * EE + e];                 // coalesced; L2-hot after first block
    a0 += hidden[(b0 + 0) * HH + h] * w;      // uniform -> scalar loads
    a1 += hidden[(b0 + 1) * HH + h] * w;
    a2 += hidden[(b0 + 2) * HH + h] * w;
    a3 += hidden[(b0 + 3) * HH + h] * w;
  }
  hb[(b0 + 0) * EE + e] = a0; hb[(b0 + 1) * EE + e] = a1;
  hb[(b0 + 2) * EE + e] = a2; hb[(b0 + 3) * EE + e] = a3;
}

// ---- fused scores + exp + unnormalized context partials ----
// grid 2048 (BS/64), block 256 (4 waves = 4 N-tiles). 64x512 enc tile lives in
// LDS bf16 (67 KB) -> 2 blocks/CU so barrier drains overlap across blocks.
// pass 1: MFMA enc@W1t (B-frags from L2), tanh, score, w=exp(score)
// pass 2: ctx partial from LDS tile; partials+sums to ws (NO atomics).
#define LDA 520   // 512 k + 8 pad shorts: 1040B row (16B-mult), 2-way banks (free)
__device__ __forceinline__ void stage_chunk(const float* __restrict__ enc,
                                            unsigned short* __restrict__ Afull,
                                            int m0, int kb, int tid) {
  int k0 = kb * 32;
#pragma unroll
  for (int t = 0; t < 2; ++t) {
    int idx = tid + t * 256;            // 512 float4 chunks: 64 rows x 8 groups
    int row = idx >> 3, kg = idx & 7;
    float4 f = *(const float4*)(enc + (size_t)(m0 + row) * HH + k0 + kg * 4);
    uint2 w; w.x = pk2(f.x, f.y); w.y = pk2(f.z, f.w);
    *(uint2*)(Afull + row * LDA + k0 + kg * 4) = w;
  }
}

__global__ __launch_bounds__(256) void k_scores(
    const float* __restrict__ enc, const unsigned short* __restrict__ W1t,
    const float* __restrict__ hb, const float* __restrict__ vw,
    float* __restrict__ attn, float* __restrict__ ctxp, float* __restrict__ sump) {
  __shared__ unsigned short Afull[64 * LDA];   // 66560 B
  __shared__ float hb_s[EE], v_s[EE];
  __shared__ float red[4 * 64];
  __shared__ float wbuf[64];

  int tid = threadIdx.x;
  int m0 = blockIdx.x * 64;
  int b = blockIdx.x >> 5;                 // 32 tiles per batch
  int sloc = (blockIdx.x & 31) * 64;
  hb_s[tid] = hb[b * EE + tid];
  v_s[tid] = vw[tid];

  int lane = tid & 63, wn = tid >> 6;      // wave = one 64-wide N tile
  int l15 = lane & 15, quad = lane >> 4;

  floatx4 acc[4][4];
#pragma unroll
  for (int i = 0; i < 4; ++i)
#pragma unroll
    for (int j = 0; j < 4; ++j) acc[i][j] = (floatx4)0.0f;

  stage_chunk(enc, Afull, m0, 0, tid);
  __syncthreads();

  for (int kb = 0; kb < 16; ++kb) {
    if (kb < 15) stage_chunk(enc, Afull, m0, kb + 1, tid);   // fills a disjoint LDS region
    int kk = kb * 32 + quad * 8;
    short8 a[4];
#pragma unroll
    for (int i = 0; i < 4; ++i)
      a[i] = *(const short8*)(Afull + (i * 16 + l15) * LDA + kk);
#pragma unroll
    for (int j = 0; j < 4; ++j) {
      short8 bfr = *(const short8*)(W1t + (wn * 64 + j * 16 + l15) * HH + kk);
#pragma unroll
      for (int i = 0; i < 4; ++i)
        acc[i][j] = __builtin_amdgcn_mfma_f32_16x16x32_bf16(a[i], bfr, acc[i][j], 0, 0, 0);
    }
    __syncthreads();
  }

  // score epilogue: score[m] = sum_e tanh(C+hb[e])*v[e]; C/D: col(e)=l15, row=quad*4+r
#pragma unroll
  for (int i = 0; i < 4; ++i)
#pragma unroll
    for (int r = 0; r < 4; ++r) {
      float s = 0.0f;
#pragma unroll
      for (int j = 0; j < 4; ++j) {
        int e = wn * 64 + j * 16 + l15;
        s += fast_tanh(acc[i][j][r] + hb_s[e]) * v_s[e];
      }
#pragma unroll
      for (int off = 1; off < 16; off <<= 1) s += __shfl_xor(s, off, 64);
      if (l15 == 0) red[wn * 64 + i * 16 + quad * 4 + r] = s;
    }
  __syncthreads();
  if (tid < 64) {
    float sc = red[tid] + red[64 + tid] + red[128 + tid] + red[192 + tid];
    float e = __builtin_amdgcn_exp2f(sc * LOG2E);   // |sc| <= sum|v| ~ 13: safe
    wbuf[tid] = e;
    attn[b * SS + sloc + tid] = e;                  // unnormalized; k_norm divides
    float s = e;
#pragma unroll
    for (int off = 1; off < 64; off <<= 1) s += __shfl_xor(s, off, 64);
    if (tid == 0) sump[blockIdx.x] = s;
  }
  __syncthreads();

  // pass 2: ctx partials from the LDS tile (enc read from HBM exactly once)
  float cx0 = 0.0f, cx1 = 0.0f;
#pragma unroll 8
  for (int r = 0; r < 64; ++r) {
    float w = wbuf[r];
    cx0 += w * bf2f(Afull[r * LDA + tid]);
    cx1 += w * bf2f(Afull[r * LDA + 256 + tid]);
  }
  ctxp[(size_t)blockIdx.x * HH + tid] = cx0;
  ctxp[(size_t)blockIdx.x * HH + 256 + tid] = cx1;
}

// ---- reduce partials, normalize attn + ctx ----
__global__ __launch_bounds__(512) void k_norm(float* __restrict__ attn,
                                              const float* __restrict__ ctxp,
                                              const float* __restrict__ sump,
                                              float* __restrict__ ctx) {
  int b = blockIdx.x, tid = threadIdx.x;
  float s = 0.0f;
#pragma unroll
  for (int t = 0; t < 32; ++t) s += sump[b * 32 + t];
  float inv = 1.0f / s;
#pragma unroll
  for (int i = 0; i < 4; ++i) attn[b * SS + tid + i * 512] *= inv;
  float c = 0.0f;
#pragma unroll
  for (int t = 0; t < 32; ++t) c += ctxp[(size_t)(b * 32 + t) * HH + tid];
  ctx[b * HH + tid] = c * inv;
}

// ---- GRU r/z gates; grid (16 b-blocks, 2 gates), block 512 (h); 4 batches/block ----
__global__ __launch_bounds__(512) void k_gates(
    const float* __restrict__ x, const float* __restrict__ ctx,
    const float* __restrict__ hidden,
    const float* __restrict__ Wxr, const float* __restrict__ Wxrb, const float* __restrict__ Whr,
    const float* __restrict__ Wxz, const float* __restrict__ Wxzb, const float* __restrict__ Whz,
    float* __restrict__ z_out, float* __restrict__ rh_out) {
  int b0 = blockIdx.x * 4, sel = blockIdx.y, h = threadIdx.x;
  const float* Wx = sel ? Wxz : Wxr;
  const float* Wh = sel ? Whz : Whr;
  const float* bias = sel ? Wxzb : Wxrb;
  float bv = bias[h];
  float a0 = bv, a1 = bv, a2 = bv, a3 = bv;
  for (int i = 0; i < INDIM; ++i) {
    float w = Wx[i * HH + h];
    a0 += x[(b0 + 0) * INDIM + i] * w; a1 += x[(b0 + 1) * INDIM + i] * w;
    a2 += x[(b0 + 2) * INDIM + i] * w; a3 += x[(b0 + 3) * INDIM + i] * w;
  }
  for (int j = 0; j < HH; ++j) {
    float w = Wx[(INDIM + j) * HH + h];
    a0 += ctx[(b0 + 0) * HH + j] * w; a1 += ctx[(b0 + 1) * HH + j] * w;
    a2 += ctx[(b0 + 2) * HH + j] * w; a3 += ctx[(b0 + 3) * HH + j] * w;
  }
  for (int j = 0; j < HH; ++j) {
    float w = Wh[j * HH + h];
    a0 += hidden[(b0 + 0) * HH + j] * w; a1 += hidden[(b0 + 1) * HH + j] * w;
    a2 += hidden[(b0 + 2) * HH + j] * w; a3 += hidden[(b0 + 3) * HH + j] * w;
  }
  float g0 = fast_sigmoid(a0), g1 = fast_sigmoid(a1);
  float g2 = fast_sigmoid(a2), g3 = fast_sigmoid(a3);
  if (sel == 0) {
    rh_out[(b0 + 0) * HH + h] = g0 * hidden[(b0 + 0) * HH + h];
    rh_out[(b0 + 1) * HH + h] = g1 * hidden[(b0 + 1) * HH + h];
    rh_out[(b0 + 2) * HH + h] = g2 * hidden[(b0 + 2) * HH + h];
    rh_out[(b0 + 3) * HH + h] = g3 * hidden[(b0 + 3) * HH + h];
  } else {
    z_out[(b0 + 0) * HH + h] = g0; z_out[(b0 + 1) * HH + h] = g1;
    z_out[(b0 + 2) * HH + h] = g2; z_out[(b0 + 3) * HH + h] = g3;
  }
}

// ---- h_tilde + new_hidden; grid 16, block 512; 4 batches/block ----
__global__ __launch_bounds__(512) void k_newh(
    const float* __restrict__ x, const float* __restrict__ ctx,
    const float* __restrict__ Wxh, const float* __restrict__ Wxhb,
    const float* __restrict__ Whh, const float* __restrict__ rh,
    const float* __restrict__ z, const float* __restrict__ hidden,
    float* __restrict__ nh, unsigned short* __restrict__ nhbf) {
  int b0 = blockIdx.x * 4, h = threadIdx.x;
  float bv = Wxhb[h];
  float a0 = bv, a1 = bv, a2 = bv, a3 = bv;
  for (int i = 0; i < INDIM; ++i) {
    float w = Wxh[i * HH + h];
    a0 += x[(b0 + 0) * INDIM + i] * w; a1 += x[(b0 + 1) * INDIM + i] * w;
    a2 += x[(b0 + 2) * INDIM + i] * w; a3 += x[(b0 + 3) * INDIM + i] * w;
  }
  for (int j = 0; j < HH; ++j) {
    float w = Wxh[(INDIM + j) * HH + h];
    a0 += ctx[(b0 + 0) * HH + j] * w; a1 += ctx[(b0 + 1) * HH + j] * w;
    a2 += ctx[(b0 + 2) * HH + j] * w; a3 += ctx[(b0 + 3) * HH + j] * w;
  }
  for (int j = 0; j < HH; ++j) {
    float w = Whh[j * HH + h];
    a0 += rh[(b0 + 0) * HH + j] * w; a1 += rh[(b0 + 1) * HH + j] * w;
    a2 += rh[(b0 + 2) * HH + j] * w; a3 += rh[(b0 + 3) * HH + j] * w;
  }
#pragma unroll
  for (int bb = 0; bb < 4; ++bb) {
    float acc = bb == 0 ? a0 : bb == 1 ? a1 : bb == 2 ? a2 : a3;
    float ht = fast_tanh(acc);
    float zz = z[(b0 + bb) * HH + h];
    float val = zz * hidden[(b0 + bb) * HH + h] + (1.0f - zz) * ht;
    nh[(b0 + bb) * HH + h] = val;
    nhbf[(b0 + bb) * HH + h] = f2bf(val);
  }
}

// ---- output projection via MFMA: out[64,32000] = nh_bf16 @ Who + bias ----
// grid 500, block 256 (4 waves); wave computes 64(M) x 16(N), K=512 full.
__global__ __launch_bounds__(256) void k_out2(const unsigned short* __restrict__ nhbf,
                                              const float* __restrict__ Who,
                                              const float* __restrict__ Whob,
                                              float* __restrict__ out) {
  int tid = threadIdx.x;
  int lane = tid & 63, w = tid >> 6;
  int l15 = lane & 15, quad = lane >> 4;
  int n = blockIdx.x * 64 + w * 16 + l15;

  floatx4 acc[4];
#pragma unroll
  for (int i = 0; i < 4; ++i) acc[i] = (floatx4)0.0f;

  for (int kc = 0; kc < 16; ++kc) {
    int k0 = kc * 32;
    float bf[8];
    const float* bp = Who + (size_t)(k0 + quad * 8) * OUTD + n;
#pragma unroll
    for (int j = 0; j < 8; ++j) bf[j] = bp[(size_t)j * OUTD];
    union { unsigned u[4]; short8 v; } bu;
#pragma unroll
    for (int j = 0; j < 4; ++j) bu.u[j] = pk2(bf[2 * j], bf[2 * j + 1]);
#pragma unroll
    for (int i = 0; i < 4; ++i) {
      short8 af = *(const short8*)(nhbf + (i * 16 + l15) * HH + k0 + quad * 8);
      acc[i] = __builtin_amdgcn_mfma_f32_16x16x32_bf16(af, bu.v, acc[i], 0, 0, 0);
    }
  }
  float bias = Whob[n];
#pragma unroll
  for (int i = 0; i < 4; ++i)
#pragma unroll
    for (int r = 0; r < 4; ++r) {
      int m = i * 16 + quad * 4 + r;
      out[(size_t)m * OUTD + n] = acc[i][r] + bias;
    }
}

extern "C" void kernel_launch(void* const* d_in, const int* in_sizes, int n_in,
                              void* d_out, int out_size, void* d_ws, size_t ws_size,
                              hipStream_t stream) {
  const float* x    = (const float*)d_in[0];
  const float* hid  = (const float*)d_in[1];
  const float* enc  = (const float*)d_in[2];
  const float* W1w  = (const float*)d_in[3];
  const float* W1b  = (const float*)d_in[4];
  const float* W2w  = (const float*)d_in[5];
  const float* vw   = (const float*)d_in[6];
  const float* Wxr  = (const float*)d_in[7];
  const float* Wxrb = (const float*)d_in[8];
  const float* Whr  = (const float*)d_in[9];
  const float* Wxz  = (const float*)d_in[10];
  const float* Wxzb = (const float*)d_in[11];
  const float* Whz  = (const float*)d_in[12];
  const float* Wxh  = (const float*)d_in[13];
  const float* Wxhb = (const float*)d_in[14];
  const float* Whh  = (const float*)d_in[15];
  const float* Who  = (const float*)d_in[16];
  const float* Whob = (const float*)d_in[17];

  float* out  = (float*)d_out;                    // [64,32000]
  float* nh   = out + (size_t)BB * OUTD;          // [64,512]
  float* attn = nh + (size_t)BB * HH;             // [64,2048]

  char* ws = (char*)d_ws;
  unsigned short* W1t  = (unsigned short*)(ws + WS_W1T);
  float* hb   = (float*)(ws + WS_HB);
  float* ctx  = (float*)(ws + WS_CTX);
  unsigned short* nhbf = (unsigned short*)(ws + WS_NHBF);
  float* zg   = (float*)(ws + WS_Z);
  float* rh   = (float*)(ws + WS_RH);
  float* ctxp = (float*)(ws + WS_CTXP);
  float* sump = (float*)(ws + WS_SUMP);

  k_prep<<<512, 256, 0, stream>>>(W1w, W1t);
  k_hb<<<16, 256, 0, stream>>>(hid, W2w, W1b, hb);
  k_scores<<<(BB * SS) / 64, 256, 0, stream>>>(enc, W1t, hb, vw, attn, ctxp, sump);
  k_norm<<<BB, 512, 0, stream>>>(attn, ctxp, sump, ctx);
  k_gates<<<dim3(16, 2), HH, 0, stream>>>(x, ctx, hid, Wxr, Wxrb, Whr, Wxz, Wxzb, Whz,
                                          zg, rh);
  k_newh<<<16, HH, 0, stream>>>(x, ctx, Wxh, Wxhb, Whh, rh, zg, hid, nh, nhbf);
  k_out2<<<500, 256, 0, stream>>>(nhbf, Who, Whob, out);
}

// Round 4
// 549.205 us; speedup vs baseline: 1.2523x; 1.2523x over previous
//
#include <hip/hip_runtime.h>

// Problem dims
#define BB 64
#define SS 2048
#define INDIM 256
#define HH 512
#define EE 256
#define OUTD 32000

typedef __attribute__((ext_vector_type(8))) short short8;
typedef __attribute__((ext_vector_type(4))) float floatx4;

#define LOG2E 1.4426950408889634f

// ---- helpers ----
__device__ __forceinline__ unsigned short f2bf(float f) {
  unsigned u = __float_as_uint(f);
  return (unsigned short)((u + 0x7FFFu + ((u >> 16) & 1u)) >> 16);  // RNE
}
__device__ __forceinline__ unsigned pk2(float a, float b) {
  return (unsigned)f2bf(a) | ((unsigned)f2bf(b) << 16);
}
__device__ __forceinline__ float bf2f(unsigned short u) {
  return __uint_as_float((unsigned)u << 16);
}
__device__ __forceinline__ float fast_tanh(float x) {
  float e = __builtin_amdgcn_exp2f(x * 2.8853900817779268f);
  return 1.0f - 2.0f * __builtin_amdgcn_rcpf(e + 1.0f);
}
__device__ __forceinline__ float fast_sigmoid(float x) {
  float e = __builtin_amdgcn_exp2f(-x * LOG2E);
  return __builtin_amdgcn_rcpf(1.0f + e);
}

// ws layout (bytes)
#define WS_W1T   0          // 256x512 bf16 W1^T              : 262144
#define WS_HBP   262144     // 2 x 64x256 f32 hb partials     : 131072
#define WS_CTX   393216     // 64x512 f32 normalized ctx      : 131072
#define WS_NHBF  524288     // 64x512 bf16 new hidden         : 65536
#define WS_Z     589824     // 64x512 f32 update gate         : 131072
#define WS_RH    720896     // 64x512 f32 r*hidden            : 131072
#define WS_GP    851968     // 20 x 64x512 f32 gate partials  : 2621440
#define WS_NP    3473408    // 10 x 64x512 f32 newh partials  : 1310720
#define WS_CTXP  4784128    // 2048x512 f32 ctx partials      : 4194304
#define WS_SUMP  8978432    // 2048 f32 exp-sum partials      : 8192

// ---- prep: transpose+convert W1 -> bf16 [e][k] ----
__global__ void k_prep(const float* __restrict__ W1, unsigned short* __restrict__ W1t) {
  int idx = blockIdx.x * 256 + threadIdx.x;   // idx = k*256 + e (coalesced read)
  int k = idx >> 8, e = idx & 255;
  W1t[e * HH + k] = f2bf(W1[idx]);
}

// ---- hb partials: hbp[seg][b][e] = (seg==0? W1b[e] : 0) + hidden[b][seg-half]@W2 ----
// grid (16 bblk, 2 kseg), block 256; each block streams 256KB of W2 (1 CU ~2us)
__global__ __launch_bounds__(256) void k_hb(const float* __restrict__ hidden,
                                            const float* __restrict__ W2,
                                            const float* __restrict__ W1b,
                                            float* __restrict__ hbp) {
  int b0 = blockIdx.x * 4, seg = blockIdx.y, e = threadIdx.x;
  int h0 = seg * 256;
  float a0 = 0, a1 = 0, a2 = 0, a3 = 0;
  if (seg == 0) { a0 = a1 = a2 = a3 = W1b[e]; }
  for (int h = 0; h < 256; ++h) {
    float w = W2[(h0 + h) * EE + e];
    a0 += hidden[(b0 + 0) * HH + h0 + h] * w;
    a1 += hidden[(b0 + 1) * HH + h0 + h] * w;
    a2 += hidden[(b0 + 2) * HH + h0 + h] * w;
    a3 += hidden[(b0 + 3) * HH + h0 + h] * w;
  }
  float* o = hbp + (size_t)seg * BB * EE;
  o[(b0 + 0) * EE + e] = a0; o[(b0 + 1) * EE + e] = a1;
  o[(b0 + 2) * EE + e] = a2; o[(b0 + 3) * EE + e] = a3;
}

// ---- fused scores + exp + unnormalized context partials ----
// grid 2048 (BS/64), block 256 (4 waves = 4 N-tiles), 64x512 enc tile in LDS bf16.
// Depth-3 register prefetch: ds_write of chunk kb consumes loads issued 3 chunks
// earlier (~600+cyc) -> no vmcnt stall; ~48KB/CU in flight -> HBM BW-bound.
#define LDA 520   // 512 k + 8 pad shorts: 1040B row (16B-mult), 2-way banks (free)
__global__ __launch_bounds__(256) void k_scores(
    const float* __restrict__ enc, const unsigned short* __restrict__ W1t,
    const float* __restrict__ hbp, const float* __restrict__ vw,
    float* __restrict__ attn, float* __restrict__ ctxp, float* __restrict__ sump) {
  __shared__ unsigned short Afull[64 * LDA];   // 66560 B
  __shared__ float hb_s[EE], v_s[EE];
  __shared__ float red[4 * 64];
  __shared__ float wbuf[64];

  int tid = threadIdx.x;
  int m0 = blockIdx.x * 64;
  int b = blockIdx.x >> 5;                 // 32 tiles per batch
  int sloc = (blockIdx.x & 31) * 64;
  hb_s[tid] = hbp[b * EE + tid] + hbp[BB * EE + b * EE + tid];
  v_s[tid] = vw[tid];

  int lane = tid & 63, wn = tid >> 6;      // wave = one 64-wide N tile
  int l15 = lane & 15, quad = lane >> 4;

  // staging assignment: thread covers (row0,kg) and (row0+32,kg), fixed all chunks
  int row0 = tid >> 3, kg = tid & 7;
  const float* base0 = enc + (size_t)(m0 + row0) * HH + kg * 4;
  const float* base1 = enc + (size_t)(m0 + 32 + row0) * HH + kg * 4;

  floatx4 acc[4][4];
#pragma unroll
  for (int i = 0; i < 4; ++i)
#pragma unroll
    for (int j = 0; j < 4; ++j) acc[i][j] = (floatx4)0.0f;

  float4 pf0[3], pf1[3];
#pragma unroll
  for (int d = 0; d < 3; ++d) {
    pf0[d] = *(const float4*)(base0 + d * 32);
    pf1[d] = *(const float4*)(base1 + d * 32);
  }

#pragma unroll
  for (int kb = 0; kb < 16; ++kb) {
    int slot = kb % 3;
    {  // ds_write chunk kb (loads issued 3 chunks ago)
      float4 f = pf0[slot];
      uint2 w; w.x = pk2(f.x, f.y); w.y = pk2(f.z, f.w);
      *(uint2*)(Afull + row0 * LDA + kb * 32 + kg * 4) = w;
      f = pf1[slot];
      uint2 w2; w2.x = pk2(f.x, f.y); w2.y = pk2(f.z, f.w);
      *(uint2*)(Afull + (row0 + 32) * LDA + kb * 32 + kg * 4) = w2;
    }
    if (kb + 3 < 16) {  // issue prefetch for chunk kb+3
      pf0[slot] = *(const float4*)(base0 + (kb + 3) * 32);
      pf1[slot] = *(const float4*)(base1 + (kb + 3) * 32);
    }
    __syncthreads();     // chunk kb visible; writes of kb+1 (next iter) are disjoint
    int kk = kb * 32 + quad * 8;
    short8 a[4];
#pragma unroll
    for (int i = 0; i < 4; ++i)
      a[i] = *(const short8*)(Afull + (i * 16 + l15) * LDA + kk);
#pragma unroll
    for (int j = 0; j < 4; ++j) {
      short8 bfr = *(const short8*)(W1t + (wn * 64 + j * 16 + l15) * HH + kk);
#pragma unroll
      for (int i = 0; i < 4; ++i)
        acc[i][j] = __builtin_amdgcn_mfma_f32_16x16x32_bf16(a[i], bfr, acc[i][j], 0, 0, 0);
    }
  }
  __syncthreads();

  // score epilogue: score[m] = sum_e tanh(C+hb[e])*v[e]; C/D: col(e)=l15, row=quad*4+r
#pragma unroll
  for (int i = 0; i < 4; ++i)
#pragma unroll
    for (int r = 0; r < 4; ++r) {
      float s = 0.0f;
#pragma unroll
      for (int j = 0; j < 4; ++j) {
        int e = wn * 64 + j * 16 + l15;
        s += fast_tanh(acc[i][j][r] + hb_s[e]) * v_s[e];
      }
#pragma unroll
      for (int off = 1; off < 16; off <<= 1) s += __shfl_xor(s, off, 64);
      if (l15 == 0) red[wn * 64 + i * 16 + quad * 4 + r] = s;
    }
  __syncthreads();
  if (tid < 64) {
    float sc = red[tid] + red[64 + tid] + red[128 + tid] + red[192 + tid];
    float e = __builtin_amdgcn_exp2f(sc * LOG2E);   // |sc| <= sum|v| ~ 13: safe
    wbuf[tid] = e;
    attn[b * SS + sloc + tid] = e;                  // unnormalized; k_norm divides
    float s = e;
#pragma unroll
    for (int off = 1; off < 64; off <<= 1) s += __shfl_xor(s, off, 64);
    if (tid == 0) sump[blockIdx.x] = s;
  }
  __syncthreads();

  // pass 2: ctx partials from the LDS tile (enc read from HBM exactly once)
  float cx0 = 0.0f, cx1 = 0.0f;
#pragma unroll 8
  for (int r = 0; r < 64; ++r) {
    float w = wbuf[r];
    cx0 += w * bf2f(Afull[r * LDA + tid]);
    cx1 += w * bf2f(Afull[r * LDA + 256 + tid]);
  }
  ctxp[(size_t)blockIdx.x * HH + tid] = cx0;
  ctxp[(size_t)blockIdx.x * HH + 256 + tid] = cx1;
}

// ---- reduce partials, normalize attn + ctx ----
__global__ __launch_bounds__(512) void k_norm(float* __restrict__ attn,
                                              const float* __restrict__ ctxp,
                                              const float* __restrict__ sump,
                                              float* __restrict__ ctx) {
  int b = blockIdx.x, tid = threadIdx.x;
  float s = 0.0f;
#pragma unroll
  for (int t = 0; t < 32; ++t) s += sump[b * 32 + t];
  float inv = 1.0f / s;
#pragma unroll
  for (int i = 0; i < 4; ++i) attn[b * SS + tid + i * 512] *= inv;
  float c = 0.0f;
#pragma unroll
  for (int t = 0; t < 32; ++t) c += ctxp[(size_t)(b * 32 + t) * HH + tid];
  ctx[b * HH + tid] = c * inv;
}

// ---- K-split partial GEMM core: 128 virtual-K rows, 4 batches ----
// virtual K layout [ x(256) | ctx(512) | hv(512) ]; hv = hidden (gates) or rh (newh)
__device__ __forceinline__ void part_seg(
    const float* __restrict__ Wx, const float* __restrict__ Wh,
    const float* __restrict__ x, const float* __restrict__ ctx,
    const float* __restrict__ hv, int seg, int b0, int h,
    float* __restrict__ outp) {
  const float* wseg;
  const float* a0; const float* a1; const float* a2; const float* a3;
  int vk0 = seg * 128;
  if (seg < 2) {
    wseg = Wx + (size_t)vk0 * HH;
    a0 = x + (b0 + 0) * INDIM + vk0;       a1 = x + (b0 + 1) * INDIM + vk0;
    a2 = x + (b0 + 2) * INDIM + vk0;       a3 = x + (b0 + 3) * INDIM + vk0;
  } else if (seg < 6) {
    wseg = Wx + (size_t)vk0 * HH;
    int off = vk0 - 256;
    a0 = ctx + (b0 + 0) * HH + off;        a1 = ctx + (b0 + 1) * HH + off;
    a2 = ctx + (b0 + 2) * HH + off;        a3 = ctx + (b0 + 3) * HH + off;
  } else {
    int off = vk0 - 768;
    wseg = Wh + (size_t)off * HH;
    a0 = hv + (b0 + 0) * HH + off;         a1 = hv + (b0 + 1) * HH + off;
    a2 = hv + (b0 + 2) * HH + off;         a3 = hv + (b0 + 3) * HH + off;
  }
  float s0 = 0, s1 = 0, s2 = 0, s3 = 0;
  for (int i = 0; i < 128; ++i) {
    float w = wseg[i * HH + h];            // coalesced vector stream (256 KB/block)
    s0 += a0[i] * w; s1 += a1[i] * w;      // scalar (wave-uniform) loads
    s2 += a2[i] * w; s3 += a3[i] * w;
  }
  outp[(b0 + 0) * HH + h] = s0; outp[(b0 + 1) * HH + h] = s1;
  outp[(b0 + 2) * HH + h] = s2; outp[(b0 + 3) * HH + h] = s3;
}

// ---- gate partials: grid (16 bblk, 10 seg, 2 sel), block 512 ----
__global__ __launch_bounds__(512) void k_gpart(
    const float* __restrict__ x, const float* __restrict__ ctx,
    const float* __restrict__ hidden,
    const float* __restrict__ Wxr, const float* __restrict__ Whr,
    const float* __restrict__ Wxz, const float* __restrict__ Whz,
    float* __restrict__ gp) {
  int b0 = blockIdx.x * 4, seg = blockIdx.y, sel = blockIdx.z, h = threadIdx.x;
  const float* Wx = sel ? Wxz : Wxr;
  const float* Wh = sel ? Whz : Whr;
  float* outp = gp + (size_t)(sel * 10 + seg) * BB * HH;
  part_seg(Wx, Wh, x, ctx, hidden, seg, b0, h, outp);
}

// ---- gate reduce: r,z = sigmoid(bias + sum partials); emit z, rh=r*hidden ----
__global__ __launch_bounds__(512) void k_gred(
    const float* __restrict__ gp, const float* __restrict__ Wxrb,
    const float* __restrict__ Wxzb, const float* __restrict__ hidden,
    float* __restrict__ z_out, float* __restrict__ rh_out) {
  int b = blockIdx.x, h = threadIdx.x;
  float r = Wxrb[h], z = Wxzb[h];
#pragma unroll
  for (int s = 0; s < 10; ++s) {
    r += gp[((size_t)s * BB + b) * HH + h];
    z += gp[((size_t)(10 + s) * BB + b) * HH + h];
  }
  r = fast_sigmoid(r);
  z_out[b * HH + h] = fast_sigmoid(z);
  rh_out[b * HH + h] = r * hidden[b * HH + h];
}

// ---- newh partials: grid (16 bblk, 10 seg), block 512; hv = rh ----
__global__ __launch_bounds__(512) void k_npart(
    const float* __restrict__ x, const float* __restrict__ ctx,
    const float* __restrict__ rh,
    const float* __restrict__ Wxh, const float* __restrict__ Whh,
    float* __restrict__ np) {
  int b0 = blockIdx.x * 4, seg = blockIdx.y, h = threadIdx.x;
  float* outp = np + (size_t)seg * BB * HH;
  part_seg(Wxh, Whh, x, ctx, rh, seg, b0, h, outp);
}

// ---- newh reduce: h~ = tanh(bias + sum); nh = z*h + (1-z)*h~; emit f32 + bf16 ----
__global__ __launch_bounds__(512) void k_nred(
    const float* __restrict__ np, const float* __restrict__ Wxhb,
    const float* __restrict__ z, const float* __restrict__ hidden,
    float* __restrict__ nh, unsigned short* __restrict__ nhbf) {
  int b = blockIdx.x, h = threadIdx.x;
  float a = Wxhb[h];
#pragma unroll
  for (int s = 0; s < 10; ++s) a += np[((size_t)s * BB + b) * HH + h];
  float ht = fast_tanh(a);
  float zz = z[b * HH + h];
  float val = zz * hidden[b * HH + h] + (1.0f - zz) * ht;
  nh[b * HH + h] = val;
  nhbf[b * HH + h] = f2bf(val);
}

// ---- output projection via MFMA: out[64,32000] = nh_bf16 @ Who + bias ----
// grid 500, block 256 (4 waves); wave computes 64(M) x 16(N), K=512 full.
__global__ __launch_bounds__(256) void k_out2(const unsigned short* __restrict__ nhbf,
                                              const float* __restrict__ Who,
                                              const float* __restrict__ Whob,
                                              float* __restrict__ out) {
  int tid = threadIdx.x;
  int lane = tid & 63, w = tid >> 6;
  int l15 = lane & 15, quad = lane >> 4;
  int n = blockIdx.x * 64 + w * 16 + l15;

  floatx4 acc[4];
#pragma unroll
  for (int i = 0; i < 4; ++i) acc[i] = (floatx4)0.0f;

#pragma unroll
  for (int kc = 0; kc < 16; ++kc) {
    int k0 = kc * 32;
    float bf[8];
    const float* bp = Who + (size_t)(k0 + quad * 8) * OUTD + n;
#pragma unroll
    for (int j = 0; j < 8; ++j) bf[j] = bp[(size_t)j * OUTD];
    union { unsigned u[4]; short8 v; } bu;
#pragma unroll
    for (int j = 0; j < 4; ++j) bu.u[j] = pk2(bf[2 * j], bf[2 * j + 1]);
#pragma unroll
    for (int i = 0; i < 4; ++i) {
      short8 af = *(const short8*)(nhbf + (i * 16 + l15) * HH + k0 + quad * 8);
      acc[i] = __builtin_amdgcn_mfma_f32_16x16x32_bf16(af, bu.v, acc[i], 0, 0, 0);
    }
  }
  float bias = Whob[n];
#pragma unroll
  for (int i = 0; i < 4; ++i)
#pragma unroll
    for (int r = 0; r < 4; ++r) {
      int m = i * 16 + quad * 4 + r;
      out[(size_t)m * OUTD + n] = acc[i][r] + bias;
    }
}

extern "C" void kernel_launch(void* const* d_in, const int* in_sizes, int n_in,
                              void* d_out, int out_size, void* d_ws, size_t ws_size,
                              hipStream_t stream) {
  const float* x    = (const float*)d_in[0];
  const float* hid  = (const float*)d_in[1];
  const float* enc  = (const float*)d_in[2];
  const float* W1w  = (const float*)d_in[3];
  const float* W1b  = (const float*)d_in[4];
  const float* W2w  = (const float*)d_in[5];
  const float* vw   = (const float*)d_in[6];
  const float* Wxr  = (const float*)d_in[7];
  const float* Wxrb = (const float*)d_in[8];
  const float* Whr  = (const float*)d_in[9];
  const float* Wxz  = (const float*)d_in[10];
  const float* Wxzb = (const float*)d_in[11];
  const float* Whz  = (const float*)d_in[12];
  const float* Wxh  = (const float*)d_in[13];
  const float* Wxhb = (const float*)d_in[14];
  const float* Whh  = (const float*)d_in[15];
  const float* Who  = (const float*)d_in[16];
  const float* Whob = (const float*)d_in[17];

  float* out  = (float*)d_out;                    // [64,32000]
  float* nh   = out + (size_t)BB * OUTD;          // [64,512]
  float* attn = nh + (size_t)BB * HH;             // [64,2048]

  char* ws = (char*)d_ws;
  unsigned short* W1t  = (unsigned short*)(ws + WS_W1T);
  float* hbp  = (float*)(ws + WS_HBP);
  float* ctx  = (float*)(ws + WS_CTX);
  unsigned short* nhbf = (unsigned short*)(ws + WS_NHBF);
  float* zg   = (float*)(ws + WS_Z);
  float* rh   = (float*)(ws + WS_RH);
  float* gp   = (float*)(ws + WS_GP);
  float* np   = (float*)(ws + WS_NP);
  float* ctxp = (float*)(ws + WS_CTXP);
  float* sump = (float*)(ws + WS_SUMP);

  k_prep<<<512, 256, 0, stream>>>(W1w, W1t);
  k_hb<<<dim3(16, 2), 256, 0, stream>>>(hid, W2w, W1b, hbp);
  k_scores<<<(BB * SS) / 64, 256, 0, stream>>>(enc, W1t, hbp, vw, attn, ctxp, sump);
  k_norm<<<BB, 512, 0, stream>>>(attn, ctxp, sump, ctx);
  k_gpart<<<dim3(16, 10, 2), 512, 0, stream>>>(x, ctx, hid, Wxr, Whr, Wxz, Whz, gp);
  k_gred<<<BB, 512, 0, stream>>>(gp, Wxrb, Wxzb, hid, zg, rh);
  k_npart<<<dim3(16, 10), 512, 0, stream>>>(x, ctx, rh, Wxh, Whh, np);
  k_nred<<<BB, 512, 0, stream>>>(np, Wxhb, zg, hid, nh, nhbf);
  k_out2<<<500, 256, 0, stream>>>(nhbf, Who, Whob, out);
}